// Round 5
// baseline (372.970 us; speedup 1.0000x reference)
//
#include <hip/hip_runtime.h>
#include <math.h>

// Problem constants: EMBED=256, HEADS=8, LEVELS=1, POINTS=4, QUEUE=2, 200x200
#define NQ    40000
#define EMB   256
#define NHEAD 8
#define HDIM  32
#define HB    200
#define WB    200
#define NCOL  192     // 128 off cols + 64 aw cols
#define HPIX  2560000 // per-head vout plane: 80000 pixels * 32 dims

typedef __attribute__((ext_vector_type(8))) __bf16 bf16x8;
typedef __attribute__((ext_vector_type(4))) float f32x4;

static __device__ __forceinline__ unsigned short f2bf(float f) {
  unsigned u = __float_as_uint(f);
  u = u + 0x7fffu + ((u >> 16) & 1u);   // round-to-nearest-even
  return (unsigned short)(u >> 16);
}
static __device__ __forceinline__ float bf2f(unsigned short s) {
  return __uint_as_float(((unsigned)s) << 16);
}
static __device__ __forceinline__ void acc8(float* a, uint4 u, float w) {
  a[0] += w * __uint_as_float(u.x << 16);
  a[1] += w * __uint_as_float(u.x & 0xffff0000u);
  a[2] += w * __uint_as_float(u.y << 16);
  a[3] += w * __uint_as_float(u.y & 0xffff0000u);
  a[4] += w * __uint_as_float(u.z << 16);
  a[5] += w * __uint_as_float(u.z & 0xffff0000u);
  a[6] += w * __uint_as_float(u.w << 16);
  a[7] += w * __uint_as_float(u.w & 0xffff0000u);
}

// ---------------------------------------------------------------------------
// conv_w: transposed bf16 weights + combined bias (tiny, one-shot)
// ---------------------------------------------------------------------------
__global__ __launch_bounds__(256) void conv_w(
    const float* __restrict__ W_off, const float* __restrict__ b_off,
    const float* __restrict__ W_attn, const float* __restrict__ b_attn,
    const float* __restrict__ W_val, const float* __restrict__ W_out,
    unsigned short* __restrict__ Wc1t, unsigned short* __restrict__ Wvt,
    unsigned short* __restrict__ Wot, float* __restrict__ bc1)
{
  int idx = blockIdx.x * 256 + threadIdx.x;
  if (idx < 98304) {                       // Wc1t [192][512]
    int n = idx >> 9, k = idx & 511;
    float v = (n < 128) ? W_off[(size_t)k * 128 + n] : W_attn[(size_t)k * 64 + (n - 128)];
    Wc1t[idx] = f2bf(v);
  } else if (idx < 163840) {               // Wvt [256][256]
    int j = idx - 98304;
    int n = j >> 8, k = j & 255;
    Wvt[j] = f2bf(W_val[(size_t)k * 256 + n]);
  } else if (idx < 229376) {               // Wot [256][256]
    int j = idx - 163840;
    int n = j >> 8, k = j & 255;
    Wot[j] = f2bf(W_out[(size_t)k * 256 + n]);
  } else if (idx < 229568) {               // bc1 [192]
    int n = idx - 229376;
    bc1[n] = (n < 128) ? b_off[n] : b_attn[n - 128];
  }
}

// ---------------------------------------------------------------------------
// Register GEMM: C[M x N] = A[M x K] @ Bt[N x K]^T + bias.
// (unchanged from round 4 except OMODE=2: head-major bf16 out for vout)
// A path: AMODE 0 = bf16 [M][K] direct; 1 = fp32 staged -> LDS; 2 = synth
// q2 = [value | query+query_pos] staged -> LDS. LDS tile XOR-swizzled in 16B
// chunks (slot = c ^ (r&7)) -> ds_read_b128 A-frags are 2-way max (free).
// Block = 256 thr = 4 waves, 1m x 4n: BM = 32, wave tile 32 x N/4.
// OMODE: 0 = fp32 direct store (+resid); 1 = bf16 row-major via LDS transpose;
//        2 = bf16 HEAD-MAJOR [head][pixel][32] via LDS transpose (k3 gathers
//            read 64 B per (head,pixel); head-major makes adjacent-x corner
//            pairs 128 B contiguous -> ~2x gather line utilization).
// ---------------------------------------------------------------------------
template<int K, int N, int AMODE, int OMODE, bool RESID>
__global__ __launch_bounds__(256, 4) void rb_gemm(
    const void* __restrict__ Aptr, const void* __restrict__ Aq2a,
    const void* __restrict__ Aq2b, const unsigned short* __restrict__ Bt,
    const float* __restrict__ bias, const float* __restrict__ resid,
    void* __restrict__ outp)
{
  constexpr int NFR = N / 64;              // 16-col n-frags per wave
  constexpr int NP  = N + 8;
  constexpr int ATB = (AMODE != 0) ? 32 * K * 2 : 0;      // A-tile bytes
  constexpr int TRB = (OMODE != 0) ? 32 * NP * 2 : 0;     // transpose bytes
  constexpr int MXB = (ATB > TRB) ? ATB : TRB;
  constexpr int LDSB = (MXB > 64) ? MXB : 64;
  __shared__ __align__(16) char lds[LDSB];
  unsigned short* trn = (unsigned short*)lds;

  const int t = threadIdx.x;
  const int m0 = blockIdx.x * 32;
  const int wid = t >> 6, lane = t & 63;
  const int wn = wid * (N / 4);
  const int lr = lane & 15, quad = lane >> 4;

  auto cvt_store = [&](int r, int c, float4 f0, float4 f1) {
    union { unsigned short us[8]; uint4 v; } u;
    u.us[0] = f2bf(f0.x); u.us[1] = f2bf(f0.y);
    u.us[2] = f2bf(f0.z); u.us[3] = f2bf(f0.w);
    u.us[4] = f2bf(f1.x); u.us[5] = f2bf(f1.y);
    u.us[6] = f2bf(f1.z); u.us[7] = f2bf(f1.w);
    *(uint4*)(lds + (size_t)r * (K * 2) + ((c ^ (r & 7)) * 16)) = u.v;
  };

  // ---- A staging: fp32 global -> bf16 LDS tile, once per block ----
  if constexpr (AMODE == 1) {
    const int c = t & 31, r0 = t >> 5;
    float4 f[4][2];
    #pragma unroll
    for (int l = 0; l < 4; l++) {
      const float* s = (const float*)Aptr + (size_t)(m0 + r0 + 8 * l) * K + c * 8;
      f[l][0] = *(const float4*)s; f[l][1] = *(const float4*)(s + 4);
    }
    #pragma unroll
    for (int l = 0; l < 4; l++)
      cvt_store(r0 + 8 * l, c, f[l][0], f[l][1]);
    __syncthreads();
  } else if constexpr (AMODE == 2) {
    const int c = t & 63, r0 = t >> 6;
    if (c < 32) {
      float4 f[8][2];
      #pragma unroll
      for (int l = 0; l < 8; l++) {
        const float* s = (const float*)Aptr + (size_t)(m0 + r0 + 4 * l) * 256 + c * 8;
        f[l][0] = *(const float4*)s; f[l][1] = *(const float4*)(s + 4);
      }
      #pragma unroll
      for (int l = 0; l < 8; l++)
        cvt_store(r0 + 4 * l, c, f[l][0], f[l][1]);
    } else {
      #pragma unroll
      for (int h = 0; h < 2; h++) {
        float4 fq[4][2], fp[4][2];
        #pragma unroll
        for (int l = 0; l < 4; l++) {
          int r = r0 + 4 * (h * 4 + l);
          const float* sq = (const float*)Aq2a + (size_t)(m0 + r) * 256 + (c - 32) * 8;
          const float* sp = (const float*)Aq2b + (size_t)(m0 + r) * 256 + (c - 32) * 8;
          fq[l][0] = *(const float4*)sq; fq[l][1] = *(const float4*)(sq + 4);
          fp[l][0] = *(const float4*)sp; fp[l][1] = *(const float4*)(sp + 4);
        }
        #pragma unroll
        for (int l = 0; l < 4; l++) {
          int r = r0 + 4 * (h * 4 + l);
          float4 f0 = make_float4(fq[l][0].x + fp[l][0].x, fq[l][0].y + fp[l][0].y,
                                  fq[l][0].z + fp[l][0].z, fq[l][0].w + fp[l][0].w);
          float4 f1 = make_float4(fq[l][1].x + fp[l][1].x, fq[l][1].y + fp[l][1].y,
                                  fq[l][1].z + fp[l][1].z, fq[l][1].w + fp[l][1].w);
          cvt_store(r, c, f0, f1);
        }
      }
    }
    __syncthreads();
  }

  f32x4 acc[2][NFR];
  #pragma unroll
  for (int i = 0; i < 2; i++)
    #pragma unroll
    for (int n = 0; n < NFR; n++) acc[i][n] = (f32x4){0.f, 0.f, 0.f, 0.f};

  auto loadB = [&](bf16x8* dst, int k0) {
    #pragma unroll
    for (int n = 0; n < NFR; n++)
      dst[n] = *(const bf16x8*)(Bt + (size_t)(wn + n * 16 + lr) * K + k0 + quad * 8);
  };
  auto loadA = [&](bf16x8* dst, int k0) {
    if constexpr (AMODE == 0) {
      const unsigned short* A = (const unsigned short*)Aptr;
      #pragma unroll
      for (int i = 0; i < 2; i++)
        dst[i] = *(const bf16x8*)(A + (size_t)(m0 + lr + i * 16) * K + k0 + quad * 8);
    } else {
      const int cb = (k0 >> 3) + quad;
      const int sw = (cb ^ (lr & 7)) * 16;
      #pragma unroll
      for (int i = 0; i < 2; i++)
        dst[i] = *(const bf16x8*)(lds + (size_t)(lr + i * 16) * (K * 2) + sw);
    }
  };

  constexpr int NK = K / 32;
  bf16x8 bcur[NFR], af[2];
  loadB(bcur, 0);
  loadA(af, 0);
  #pragma unroll
  for (int ks = 0; ks < NK; ks++) {
    bf16x8 bnxt[NFR], anxt[2];
    if (ks + 1 < NK) {                     // prefetch next k-step ahead of MFMAs
      loadB(bnxt, (ks + 1) * 32);
      loadA(anxt, (ks + 1) * 32);
    }
    #pragma unroll
    for (int i = 0; i < 2; i++)
      #pragma unroll
      for (int n = 0; n < NFR; n++)
        acc[i][n] = __builtin_amdgcn_mfma_f32_16x16x32_bf16(af[i], bcur[n], acc[i][n], 0, 0, 0);
    if (ks + 1 < NK) {
      #pragma unroll
      for (int n = 0; n < NFR; n++) bcur[n] = bnxt[n];
      af[0] = anxt[0]; af[1] = anxt[1];
    }
  }

  // epilogue: C/D layout col=lane&15, row=quad*4+reg
  if constexpr (OMODE == 0) {
    #pragma unroll
    for (int i = 0; i < 2; i++) {
      int rowb = m0 + i * 16 + quad * 4;
      #pragma unroll
      for (int n = 0; n < NFR; n++) {
        int col = wn + n * 16 + lr;
        float bsv = bias[col];
        #pragma unroll
        for (int r = 0; r < 4; r++) {
          int rr = rowb + r;
          float v = acc[i][n][r] + bsv;
          if (RESID) v += resid[(size_t)rr * N + col];
          ((float*)outp)[(size_t)rr * N + col] = v;
        }
      }
    }
  } else {
    // bf16 out via LDS transpose -> full-line uint4 stores.
    if constexpr (AMODE != 0) __syncthreads();   // A-tile -> trn buffer reuse
    #pragma unroll
    for (int i = 0; i < 2; i++) {
      #pragma unroll
      for (int n = 0; n < NFR; n++) {
        int col = wn + n * 16 + lr;
        float bsv = bias[col];
        #pragma unroll
        for (int r = 0; r < 4; r++) {
          int rl = i * 16 + quad * 4 + r;
          trn[rl * NP + col] = f2bf(acc[i][n][r] + bsv);
        }
      }
    }
    __syncthreads();
    constexpr int NCH = (32 * N) / 2048;   // uint4 chunks per thread
    #pragma unroll
    for (int l = 0; l < NCH; l++) {
      int c = t + l * 256;
      int row = c / (N / 8);
      int coloff = (c % (N / 8)) * 8;
      uint4 d = *(const uint4*)(trn + row * NP + coloff);
      unsigned short* op = (unsigned short*)outp;
      if constexpr (OMODE == 2)
        op += (size_t)(coloff >> 5) * HPIX + (size_t)(m0 + row) * 32 + (coloff & 31);
      else
        op += (size_t)(m0 + row) * N + coloff;
      *(uint4*)op = d;
    }
  }
}

// ---------------------------------------------------------------------------
// K3: deformable sampling + queue mean. Round-5 rebuild:
//   - 8 queries/block (5000 blocks), vout is HEAD-MAJOR [head][pixel][32].
//   - gather thread = (query, head, 8-dim chunk); each corner read is one
//     uint4 (16 B) -> 4x fewer mem instructions than the 4 B version, 32
//     independent loads in flight per thread.
//   - accumulation order (b outer, p inner, corners x.y.z.w) identical to
//     the previous version -> bit-identical output.
// ---------------------------------------------------------------------------
__global__ __launch_bounds__(256) void k3_sample(
    const unsigned short* __restrict__ raw1, const float* __restrict__ refp,
    const unsigned short* __restrict__ vh, unsigned short* __restrict__ msd)
{
  __shared__ int4   sidx[8][64];   // pixel indices (queue-offset included)
  __shared__ float4 swgt[8][64];
  const int t = threadIdx.x;
  const int q0 = blockIdx.x * 8;

  #pragma unroll
  for (int ee = 0; ee < 2; ee++) {
    const int e = t + ee * 256;          // 512 entries: 8q x 2b x 8h x 4p
    const int qi = e >> 6, r6 = e & 63;
    const int b = r6 >> 5, h = (r6 >> 2) & 7, p = r6 & 3;
    const int q = q0 + qi;
    const unsigned short* r = raw1 + (size_t)q * NCOL;
    float ox = bf2f(r[h * 16 + b * 8 + p * 2 + 0]);
    float oy = bf2f(r[h * 16 + b * 8 + p * 2 + 1]);
    float l0 = bf2f(r[128 + h * 8 + b * 4 + 0]);
    float l1 = bf2f(r[128 + h * 8 + b * 4 + 1]);
    float l2 = bf2f(r[128 + h * 8 + b * 4 + 2]);
    float l3 = bf2f(r[128 + h * 8 + b * 4 + 3]);
    float mx = fmaxf(fmaxf(l0, l1), fmaxf(l2, l3));
    float e0 = expf(l0 - mx), e1 = expf(l1 - mx);
    float e2 = expf(l2 - mx), e3 = expf(l3 - mx);
    float ssum = e0 + e1 + e2 + e3;
    float ep = (p == 0) ? e0 : (p == 1) ? e1 : (p == 2) ? e2 : e3;
    float aw = ep / ssum * 0.5f;          // fold queue-mean 0.5
    float rx = refp[((size_t)b * NQ + q) * 2 + 0];
    float ry = refp[((size_t)b * NQ + q) * 2 + 1];
    float px = rx * (float)WB + ox - 0.5f;
    float py = ry * (float)HB + oy - 0.5f;
    float x0f = floorf(px), y0f = floorf(py);
    float lx = px - x0f, ly = py - y0f;
    int x0 = (int)x0f, y0 = (int)y0f, x1 = x0 + 1, y1 = y0 + 1;
    int x0c = min(max(x0, 0), WB - 1), x1c = min(max(x1, 0), WB - 1);
    int y0c = min(max(y0, 0), HB - 1), y1c = min(max(y1, 0), HB - 1);
    float vx0 = ((unsigned)x0 < (unsigned)WB) ? 1.f : 0.f;
    float vx1 = ((unsigned)x1 < (unsigned)WB) ? 1.f : 0.f;
    float vy0 = ((unsigned)y0 < (unsigned)HB) ? 1.f : 0.f;
    float vy1 = ((unsigned)y1 < (unsigned)HB) ? 1.f : 0.f;
    const int pb = b * NQ;               // per-queue pixel plane offset
    int4 ix;
    ix.x = pb + y0c * WB + x0c;
    ix.y = pb + y0c * WB + x1c;
    ix.z = pb + y1c * WB + x0c;
    ix.w = pb + y1c * WB + x1c;
    float4 wv;
    wv.x = aw * (1.f - lx) * (1.f - ly) * vx0 * vy0;
    wv.y = aw * lx * (1.f - ly) * vx1 * vy0;
    wv.z = aw * (1.f - lx) * ly * vx0 * vy1;
    wv.w = aw * lx * ly * vx1 * vy1;
    sidx[qi][r6] = ix;
    swgt[qi][r6] = wv;
  }
  __syncthreads();

  // gather: thread = (qi, h, c); reads vh[h][pixel][c*8 .. c*8+8) as uint4
  const int qi = t >> 5, h = (t >> 2) & 7, c = t & 3;
  const unsigned short* vb = vh + (size_t)h * HPIX + c * 8;
  float a[8];
  #pragma unroll
  for (int j = 0; j < 8; j++) a[j] = 0.f;
  #pragma unroll
  for (int b = 0; b < 2; b++) {
    #pragma unroll
    for (int p = 0; p < 4; p++) {
      int ent = b * 32 + h * 4 + p;
      int4 pix = sidx[qi][ent];
      float4 wv = swgt[qi][ent];
      uint4 v00 = *(const uint4*)(vb + (size_t)pix.x * 32);
      uint4 v10 = *(const uint4*)(vb + (size_t)pix.y * 32);
      uint4 v01 = *(const uint4*)(vb + (size_t)pix.z * 32);
      uint4 v11 = *(const uint4*)(vb + (size_t)pix.w * 32);
      acc8(a, v00, wv.x);
      acc8(a, v10, wv.y);
      acc8(a, v01, wv.z);
      acc8(a, v11, wv.w);
    }
  }
  union { unsigned short us[8]; uint4 v; } o;
  #pragma unroll
  for (int j = 0; j < 8; j++) o.us[j] = f2bf(a[j]);
  *(uint4*)(msd + (size_t)(q0 + qi) * EMB + h * HDIM + c * 8) = o.v;
}

// ---------------------------------------------------------------------------
extern "C" void kernel_launch(void* const* d_in, const int* in_sizes, int n_in,
                              void* d_out, int out_size, void* d_ws, size_t ws_size,
                              hipStream_t stream) {
  const float* query     = (const float*)d_in[0];
  const float* query_pos = (const float*)d_in[1];
  const float* value     = (const float*)d_in[2];
  const float* refp      = (const float*)d_in[3];
  // d_in[4]: spatial_shapes constant [200,200]
  const float* W_off  = (const float*)d_in[5];
  const float* b_off  = (const float*)d_in[6];
  const float* W_attn = (const float*)d_in[7];
  const float* b_attn = (const float*)d_in[8];
  const float* W_val  = (const float*)d_in[9];
  const float* b_val  = (const float*)d_in[10];
  const float* W_out  = (const float*)d_in[11];
  const float* b_out  = (const float*)d_in[12];
  float* out = (float*)d_out;

  char* ws = (char*)d_ws;
  unsigned short* raw1 = (unsigned short*)(ws);            // 40000*192*2 = 15,360,000
  unsigned short* vout = (unsigned short*)(ws + 15360000); // 80000*256*2 = 40,960,000 (head-major)
  unsigned short* msdb = (unsigned short*)(ws + 56320000); // 40000*256*2 = 20,480,000
  unsigned short* Wc1t = (unsigned short*)(ws + 76800000); // 192*512*2
  unsigned short* Wvt  = (unsigned short*)(ws + 76996608); // 256*256*2
  unsigned short* Wot  = (unsigned short*)(ws + 77127680); // 256*256*2
  float*          bc1  = (float*)(ws + 77258752);          // 192*4

  hipLaunchKernelGGL(conv_w, dim3(897), dim3(256), 0, stream,
                     W_off, b_off, W_attn, b_attn, W_val, W_out, Wc1t, Wvt, Wot, bc1);

  // k1: raw1 = q2 @ [W_off|W_attn] + bc1  (40000x512 @ 512x192), staged synth A, bf16 out
  hipLaunchKernelGGL((rb_gemm<512, 192, 2, 1, false>),
                     dim3(1250), dim3(256), 0, stream,
                     (const void*)value, (const void*)query, (const void*)query_pos,
                     Wc1t, bc1, (const float*)nullptr, (void*)raw1);
  // k2: v = value @ W_val + b_val  (80000x256 @ 256x256), staged fp32 A, head-major bf16 out
  hipLaunchKernelGGL((rb_gemm<256, 256, 1, 2, false>),
                     dim3(2500), dim3(256), 0, stream,
                     (const void*)value, (const void*)nullptr, (const void*)nullptr,
                     Wvt, b_val, (const float*)nullptr, (void*)vout);
  // k3: sampling + queue mean -> msd bf16 (8 q/block, uint4 gathers)
  hipLaunchKernelGGL(k3_sample, dim3(NQ / 8), dim3(256), 0, stream,
                     raw1, refp, vout, msdb);
  // k4: out = msd @ W_out + b_out + query  (40000x256 @ 256x256), bf16 A direct, fp32 out + resid
  hipLaunchKernelGGL((rb_gemm<256, 256, 0, 0, true>),
                     dim3(1250), dim3(256), 0, stream,
                     (const void*)msdb, (const void*)nullptr, (const void*)nullptr,
                     Wot, b_out, query, (void*)out);
}